// Round 8
// baseline (450.239 us; speedup 1.0000x reference)
//
#include <hip/hip_runtime.h>
#include <hip/hip_bf16.h>
#include <cstdint>

#define NODES 50000
#define EDGES 400000
#define FIN   988
#define KP0   992      // FIN padded to multiple of 32
#define FH    256
#define FC    47

typedef __attribute__((ext_vector_type(8))) short short8;
typedef __attribute__((ext_vector_type(4))) float f32x4;

__device__ __forceinline__ ushort f2bf(float x) {      // RNE f32 -> bf16
    union { float f; uint32_t u; } v; v.f = x;
    uint32_t r = v.u + 0x7FFF + ((v.u >> 16) & 1);
    return (ushort)(r >> 16);
}
__device__ __forceinline__ float bf2f(ushort u) {
    union { uint32_t u; float f; } v; v.u = ((uint32_t)u) << 16;
    return v.f;
}
__device__ __forceinline__ uint32_t cvtpk_bf(float lo, float hi) {  // RNE pack
    uint32_t r;
    asm("v_cvt_pk_bf16_f32 %0, %1, %2" : "=v"(r) : "v"(lo), "v"(hi));
    return r;
}
__device__ __forceinline__ void g2l16(const void* g, void* l) {
    __builtin_amdgcn_global_load_lds((const __attribute__((address_space(1))) void*)g,
                                     (__attribute__((address_space(3))) void*)l, 16, 0, 0);
}

// ---------------- CSR build ----------------
__global__ void k_deg_count(const int* __restrict__ dst, int* __restrict__ deg, int nE) {
    int i = blockIdx.x * blockDim.x + threadIdx.x;
    if (i < nE) atomicAdd(&deg[dst[i]], 1);
}

__global__ __launch_bounds__(1024) void k_scan(const int* __restrict__ deg,
                                               int* __restrict__ rowptr,
                                               int* __restrict__ cursor, int n) {
    __shared__ int sums[1024];
    const int t = threadIdx.x;
    const int chunk = (n + 1023) / 1024;
    const int b = t * chunk;
    const int e = min(b + chunk, n);
    int s = 0;
    for (int i = b; i < e; ++i) s += deg[i];
    sums[t] = s;
    __syncthreads();
    for (int off = 1; off < 1024; off <<= 1) {
        int v = 0;
        if (t >= off) v = sums[t - off];
        __syncthreads();
        if (t >= off) sums[t] += v;
        __syncthreads();
    }
    int excl = (t == 0) ? 0 : sums[t - 1];
    for (int i = b; i < e; ++i) {
        int d = deg[i];
        rowptr[i] = excl;
        cursor[i] = excl;
        excl += d;
    }
    if (t == 1023) rowptr[n] = sums[1023];
}

__global__ void k_fill(const int* __restrict__ src, const int* __restrict__ dst,
                       int* __restrict__ cursor, int* __restrict__ eidx, int nE) {
    int i = blockIdx.x * blockDim.x + threadIdx.x;
    if (i < nE) {
        int d = dst[i];
        int p = atomicAdd(&cursor[d], 1);
        eidx[p] = src[i];
    }
}

// ---------------- merged weight transpose+convert, PRE-SWIZZLED ----------------
// Stored layout: within each 64B (32-bf16) K-chunk of row n, 16B slot
// slot_stored = slot_logical ^ ((n>>1)&3). (Key period 8 -> the 8 same-bank
// rows of a frag read map to 4 slots x2 = free 2-way, per m136.)
#define W0E (512 * KP0)
#define W1E (512 * FH)
#define W2E (128 * FH)
__global__ void k_cvtw(const float* __restrict__ Ws0, const float* __restrict__ Wn0,
                       const float* __restrict__ Ws1, const float* __restrict__ Wn1,
                       const float* __restrict__ Ws2, const float* __restrict__ Wn2,
                       ushort* __restrict__ Wt0, ushort* __restrict__ Wt1,
                       ushort* __restrict__ Wt2) {
    int gid = blockIdx.x * blockDim.x + threadIdx.x;
    if (gid < W0E) {
        int n = gid / KP0, ks = gid - n * KP0;
        int kl = (ks & ~31) + ((((ks >> 3) & 3) ^ ((n >> 1) & 3)) << 3) + (ks & 7);
        float v = 0.f;
        if (kl < FIN) v = (n < FH) ? Ws0[(size_t)kl * FH + n] : Wn0[(size_t)kl * FH + (n - FH)];
        Wt0[gid] = f2bf(v);
    } else if (gid < W0E + W1E) {
        int g = gid - W0E;
        int n = g >> 8, ks = g & 255;
        int kl = (ks & ~31) + ((((ks >> 3) & 3) ^ ((n >> 1) & 3)) << 3) + (ks & 7);
        float v = (n < FH) ? Ws1[(size_t)kl * FH + n] : Wn1[(size_t)kl * FH + (n - FH)];
        Wt1[g] = f2bf(v);
    } else if (gid < W0E + W1E + W2E) {
        int g = gid - W0E - W1E;
        int n = g >> 8, ks = g & 255;
        int kl = (ks & ~31) + ((((ks >> 3) & 3) ^ ((n >> 1) & 3)) << 3) + (ks & 7);
        float v = 0.f;
        if (n < FC) v = Ws2[(size_t)kl * FC + n];
        else if (n >= 64 && n < 64 + FC) v = Wn2[(size_t)kl * FC + (n - 64)];
        Wt2[g] = f2bf(v);
    }
}

// ---------------- bf16 MFMA GEMM: gload_lds + counted-vmcnt double-buffer ----------------
// C[M][ldc](bf16) = A[M][lda] @ Bt[N][Kpad]^T. 128x128 tile, BK=32, 4 waves,
// 4x4 16x16x32 frags/wave. Staging via global_load_lds only (no staging regs).
// Two K-tiles in flight: per iter, wait vmcnt(NLD) (NOT 0 -> next tile's loads
// stay in flight across the barrier, T4/m218 mechanism), compute, then stage
// tile k+2 into the buffer just read. vmcnt completes in order (m135), so
// vmcnt(NLD) == "tile k fully resident".
#define BMT 128
#define BKT 32

template<int AF32>
__global__ __launch_bounds__(256, 4) void k_mm(const void* __restrict__ Ap,
                                               const ushort* __restrict__ Bt,
                                               ushort* __restrict__ C,
                                               const int M, const int lda,
                                               const int Kpad, const int ldc,
                                               const int nbx) {
    // bijective XCD-chunk swizzle (safe for nwg % 8 != 0)
    const int nwg = gridDim.x;
    const int bid = blockIdx.x;
    const int q = nwg >> 3, r = nwg & 7;
    const int xcd = bid & 7, ii = bid >> 3;
    const int swz = (xcd < r ? xcd * (q + 1) : r * (q + 1) + (xcd - r) * q) + ii;
    const int bm = (swz / nbx) * BMT;
    const int bn = (swz % nbx) * BMT;

    constexpr int ABUF = AF32 ? 8192 : 4096;   // ushorts per A buffer
    constexpr int BBUF = 4096;
    __shared__ ushort As[2 * ABUF];
    __shared__ ushort Bs[2 * BBUF];
    const float* Asf = (const float*)As;

    const int t = threadIdx.x;
    const int wid = t >> 6, lane = t & 63;
    const int wr = (wid >> 1) * 64, wc = (wid & 1) * 64;
    const int lr = lane & 15, g = lane >> 4;

    f32x4 acc[4][4] = {};

    // ---- staging descriptors ----
    const ushort* bsrc[2]; ushort* bdst[2];
#pragma unroll
    for (int j = 0; j < 2; ++j) {
        const int c = j * 4 + wid;                 // 1KB chunk 0..7
        const int row = c * 16 + (lane >> 2);      // 64B rows
        bsrc[j] = Bt + (size_t)(bn + row) * Kpad + ((lane & 3) << 3);
        bdst[j] = &Bs[c * 512];
    }
    const float*  asrcf[4]; ushort* adstf[4];
    const ushort* asrcb[2]; ushort* adstb[2];
    const float* aend = nullptr;
    if (AF32) {
        const float* A = (const float*)Ap;
        aend = A + ((size_t)M * lda - 4);          // clamp: last valid 16B of A
#pragma unroll
        for (int j = 0; j < 4; ++j) {              // 16KB = 4 issues
            const int c = j * 4 + wid;             // chunk 0..15
            const int row = c * 8 + (lane >> 3);   // 128B rows
            const int arow = min(bm + row, M - 1);
            const int scol = ((lane & 7) ^ (row & 7)) << 2;  // inverse swizzle (f32 key row&7)
            asrcf[j] = A + (size_t)arow * lda + scol;
            adstf[j] = &As[c * 512];
        }
    } else {
        const ushort* A = (const ushort*)Ap;
#pragma unroll
        for (int j = 0; j < 2; ++j) {
            const int c = j * 4 + wid;
            const int row = c * 16 + (lane >> 2);
            const int arow = min(bm + row, M - 1);
            asrcb[j] = A + (size_t)arow * lda + ((lane & 3) << 3);  // hbuf pre-swizzled
            adstb[j] = &As[c * 512];
        }
    }

    // ---- frag-read offsets (swizzle-matched, hoisted) ----
    int roB[4], roA0[4], roA1[4];
#pragma unroll
    for (int n = 0; n < 4; ++n) {
        const int col = wc + n * 16 + lr;
        roB[n] = col * 32 + ((g ^ ((col >> 1) & 3)) << 3);
    }
#pragma unroll
    for (int m = 0; m < 4; ++m) {
        const int row = wr + m * 16 + lr;
        if (AF32) {   // f32 elem offsets, two 16B slots per frag, key row&7
            roA0[m] = row * 32 + (((2 * g) ^ (row & 7)) << 2);
            roA1[m] = row * 32 + (((2 * g + 1) ^ (row & 7)) << 2);
        } else {      // bf16, key (row>>1)&3
            roA0[m] = row * 32 + ((g ^ ((row >> 1) & 3)) << 3);
            roA1[m] = 0;
        }
    }

    auto stage = [&](int k0, int h) {
        if constexpr (AF32) {
#pragma unroll
            for (int j = 0; j < 4; ++j) {
                const float* p = asrcf[j] + k0;
                p = (p > aend) ? aend : p;   // OOB clamp lands in zero-weight K-pad cols
                g2l16(p, adstf[j] + h * ABUF);
            }
        } else {
#pragma unroll
            for (int j = 0; j < 2; ++j) g2l16(asrcb[j] + k0, adstb[j] + h * ABUF);
        }
#pragma unroll
        for (int j = 0; j < 2; ++j) g2l16(bsrc[j] + k0, bdst[j] + h * BBUF);
    };

    const int nt = Kpad / BKT;
    stage(0, 0);
    if (nt > 1) stage(BKT, 1);

    int h = 0;
    for (int it = 0; it < nt; ++it, h ^= 1) {
        if (it + 1 < nt) {   // next tile in flight: wait only for tile `it`
            if constexpr (AF32) asm volatile("s_waitcnt vmcnt(6)" ::: "memory");
            else                asm volatile("s_waitcnt vmcnt(4)" ::: "memory");
        } else {
            asm volatile("s_waitcnt vmcnt(0)" ::: "memory");
        }
        __builtin_amdgcn_s_barrier();   // all waves: tile `it` resident

        const ushort* Ab = &As[h * ABUF];
        const float*  Abf = (const float*)Ab;
        const ushort* Bb = &Bs[h * BBUF];
        short8 af[4], bfr[4];
        if constexpr (AF32) {
#pragma unroll
            for (int m = 0; m < 4; ++m) {
                const f32x4 lo = *(const f32x4*)&Abf[roA0[m]];
                const f32x4 hi = *(const f32x4*)&Abf[roA1[m]];
                union { uint32_t u[4]; short8 s; } pk;
                pk.u[0] = cvtpk_bf(lo[0], lo[1]);
                pk.u[1] = cvtpk_bf(lo[2], lo[3]);
                pk.u[2] = cvtpk_bf(hi[0], hi[1]);
                pk.u[3] = cvtpk_bf(hi[2], hi[3]);
                af[m] = pk.s;
            }
        } else {
#pragma unroll
            for (int m = 0; m < 4; ++m) af[m] = *(const short8*)&Ab[roA0[m]];
        }
#pragma unroll
        for (int n = 0; n < 4; ++n) bfr[n] = *(const short8*)&Bb[roB[n]];

        asm volatile("s_waitcnt lgkmcnt(0)" ::: "memory");
        __builtin_amdgcn_sched_barrier(0);
        __builtin_amdgcn_s_barrier();   // all waves done reading buf[h]

        if (it + 2 < nt) stage((it + 2) * BKT, h);   // overwrite buf[h] under MFMA

#pragma unroll
        for (int m = 0; m < 4; ++m)
#pragma unroll
            for (int n = 0; n < 4; ++n)
                acc[m][n] = __builtin_amdgcn_mfma_f32_16x16x32_bf16(af[m], bfr[n], acc[m][n], 0, 0, 0);
    }

#pragma unroll
    for (int m = 0; m < 4; ++m) {
#pragma unroll
        for (int i = 0; i < 4; ++i) {
            const int row = bm + wr + m * 16 + g * 4 + i;
            if (row >= M) continue;
#pragma unroll
            for (int n = 0; n < 4; ++n) {
                const int col = bn + wc + n * 16 + lr;
                C[(size_t)row * ldc + col] = f2bf(acc[m][n][i]);
            }
        }
    }
}

// ---------------- fused gather-aggregate + combine, F=256 ----------------
// hbuf written PRE-SWIZZLED (slot ^ ((node>>1)&3)) for the next GEMM's A staging.
__global__ void k_gac256(const ushort* __restrict__ C, const int* __restrict__ rowptr,
                         const int* __restrict__ eidx, const float* __restrict__ bias,
                         ushort* __restrict__ hout) {
    int gid = blockIdx.x * blockDim.x + threadIdx.x;
    int node = gid >> 6;
    if (node >= NODES) return;
    const int l4 = (gid & 63) << 2;
    const int beg = rowptr[node];
    const int end = rowptr[node + 1];
    float a0 = 0.f, a1 = 0.f, a2 = 0.f, a3 = 0.f;
    int e = beg;
    for (; e + 1 < end; e += 2) {
        const int s0 = eidx[e], s1 = eidx[e + 1];
        const ushort4 v0 = *(const ushort4*)&C[(size_t)s0 * 512 + 256 + l4];
        const ushort4 v1 = *(const ushort4*)&C[(size_t)s1 * 512 + 256 + l4];
        a0 += bf2f(v0.x) + bf2f(v1.x);
        a1 += bf2f(v0.y) + bf2f(v1.y);
        a2 += bf2f(v0.z) + bf2f(v1.z);
        a3 += bf2f(v0.w) + bf2f(v1.w);
    }
    if (e < end) {
        const int s = eidx[e];
        const ushort4 v = *(const ushort4*)&C[(size_t)s * 512 + 256 + l4];
        a0 += bf2f(v.x); a1 += bf2f(v.y); a2 += bf2f(v.z); a3 += bf2f(v.w);
    }
    const float inv = 1.f / (float)max(end - beg, 1);
    const ushort4 hs = *(const ushort4*)&C[(size_t)node * 512 + l4];
    const f32x4 bv = *(const f32x4*)&bias[l4];
    ushort4 w;
    w.x = f2bf(fmaxf(bf2f(hs.x) + a0 * inv + bv[0], 0.f));
    w.y = f2bf(fmaxf(bf2f(hs.y) + a1 * inv + bv[1], 0.f));
    w.z = f2bf(fmaxf(bf2f(hs.z) + a2 * inv + bv[2], 0.f));
    w.w = f2bf(fmaxf(bf2f(hs.w) + a3 * inv + bv[3], 0.f));
    const int scol = (l4 & ~31) + ((((l4 >> 3) & 3) ^ ((node >> 1) & 3)) << 3) + (l4 & 7);
    *(ushort4*)&hout[(size_t)node * 256 + scol] = w;
}

// ---------------- final layer gather, F=47, C2 bf16 [50000][128] ----------------
__global__ void k_gac47(const ushort* __restrict__ C, const int* __restrict__ rowptr,
                        const int* __restrict__ eidx, const float* __restrict__ bias,
                        float* __restrict__ out) {
    int gid = blockIdx.x * blockDim.x + threadIdx.x;
    int node = gid >> 6;
    if (node >= NODES) return;
    const int l = gid & 63;
    if (l >= FC) return;
    const int beg = rowptr[node];
    const int end = rowptr[node + 1];
    float acc = 0.f;
    int e = beg;
    for (; e + 1 < end; e += 2) {
        const int s0 = eidx[e], s1 = eidx[e + 1];
        acc += bf2f(C[(size_t)s0 * 128 + 64 + l]) + bf2f(C[(size_t)s1 * 128 + 64 + l]);
    }
    if (e < end) acc += bf2f(C[(size_t)eidx[e] * 128 + 64 + l]);
    const float inv = 1.f / (float)max(end - beg, 1);
    out[(size_t)node * FC + l] = bf2f(C[(size_t)node * 128 + l]) + acc * inv + bias[l];
}

extern "C" void kernel_launch(void* const* d_in, const int* in_sizes, int n_in,
                              void* d_out, int out_size, void* d_ws, size_t ws_size,
                              hipStream_t stream) {
    const float* x       = (const float*)d_in[0];
    const int*   src     = (const int*)d_in[1];
    const int*   dst     = (const int*)d_in[2];
    const float* Wself0  = (const float*)d_in[3];
    const float* Wneigh0 = (const float*)d_in[4];
    const float* b0      = (const float*)d_in[5];
    const float* Wself1  = (const float*)d_in[6];
    const float* Wneigh1 = (const float*)d_in[7];
    const float* b1      = (const float*)d_in[8];
    const float* Wself2  = (const float*)d_in[9];
    const float* Wneigh2 = (const float*)d_in[10];
    const float* b2      = (const float*)d_in[11];
    float* out = (float*)d_out;

    char* w = (char*)d_ws;
    ushort* Cbuf = (ushort*)w;   w += (size_t)NODES * 512 * 2;   // 51.2 MB
    ushort* hbuf = (ushort*)w;   w += (size_t)NODES * FH * 2;    // 25.6 MB
    ushort* Wt0  = (ushort*)w;   w += (size_t)W0E * 2;
    ushort* Wt1  = (ushort*)w;   w += (size_t)W1E * 2;
    ushort* Wt2  = (ushort*)w;   w += (size_t)W2E * 2;
    int* rowptr  = (int*)w;      w += (NODES + 1) * sizeof(int);
    int* cursor  = (int*)w;      w += NODES * sizeof(int);
    int* eidx    = (int*)w;

    dim3 blk(256);

    // ---- CSR build ----
    hipMemsetAsync(cursor, 0, NODES * sizeof(int), stream);
    k_deg_count<<<(EDGES + 255) / 256, blk, 0, stream>>>(dst, cursor, EDGES);
    k_scan<<<1, 1024, 0, stream>>>(cursor, rowptr, cursor, NODES);
    k_fill<<<(EDGES + 255) / 256, blk, 0, stream>>>(src, dst, cursor, eidx, EDGES);

    // ---- weight convert (pre-swizzled) ----
    k_cvtw<<<(W0E + W1E + W2E + 255) / 256, blk, 0, stream>>>(
        Wself0, Wneigh0, Wself1, Wneigh1, Wself2, Wneigh2, Wt0, Wt1, Wt2);

    const int gat_blocks = (int)(((size_t)NODES * 64 + 255) / 256);
    const int nbyM = (NODES + BMT - 1) / BMT;   // 391

    // ---- Layer 0: C0 = x @ [Wself0|Wneigh0]  (f32 A staged raw, cvt at read) ----
    k_mm<1><<<dim3(4 * nbyM), blk, 0, stream>>>(x, Wt0, Cbuf, NODES, FIN, KP0, 512, 4);
    k_gac256<<<gat_blocks, blk, 0, stream>>>(Cbuf, rowptr, eidx, b0, hbuf);

    // ---- Layer 1: C1 = h1 @ [Wself1|Wneigh1]  (K=256) ----
    k_mm<0><<<dim3(4 * nbyM), blk, 0, stream>>>(hbuf, Wt1, Cbuf, NODES, FH, FH, 512, 4);
    k_gac256<<<gat_blocks, blk, 0, stream>>>(Cbuf, rowptr, eidx, b1, hbuf);

    // ---- Layer 2: C2 = h2 @ [Wself2|Wneigh2 padded]  (N=128, K=256) ----
    k_mm<0><<<dim3(nbyM), blk, 0, stream>>>(hbuf, Wt2, Cbuf, NODES, FH, FH, 128, 1);
    k_gac47<<<gat_blocks, blk, 0, stream>>>(Cbuf, rowptr, eidx, b2, out);
}